// Round 7
// baseline (405.320 us; speedup 1.0000x reference)
//
#include <hip/hip_runtime.h>
#include <hip/hip_bf16.h>

#define A_N 16
#define B_N 8192
#define O_N 128
#define ACT_N 16
#define H_N 128
#define NH_N 4
#define D_N 32
#define IN_N 144
#define NEGV -1e9f

typedef __attribute__((ext_vector_type(8))) short short8;
typedef __attribute__((ext_vector_type(4))) float floatx4;

// ---- bf16 helpers (RNE) -------------------------------------------------
static __device__ inline unsigned short f2bf(float f) {
    union { float f; unsigned u; } x{f};
    unsigned u = x.u + 0x7FFFu + ((x.u >> 16) & 1u);
    return (unsigned short)(u >> 16);
}
static __device__ inline unsigned pack_bf2(float a, float b) {
    union { float f; unsigned u; } xa{a}, xb{b};
    unsigned ua = xa.u + 0x7FFFu + ((xa.u >> 16) & 1u);
    unsigned ub = xb.u + 0x7FFFu + ((xb.u >> 16) & 1u);
    return (ua >> 16) | (ub & 0xFFFF0000u);
}
static __device__ inline float bf2f(unsigned short h) {
    union { unsigned u; float f; } x;
    x.u = ((unsigned)h) << 16;
    return x.f;
}
static __device__ inline float bflo(unsigned u) {
    union { unsigned u; float f; } x; x.u = u << 16; return x.f;
}
static __device__ inline float bfhi(unsigned u) {
    union { unsigned u; float f; } x; x.u = u & 0xFFFF0000u; return x.f;
}
static __device__ inline short8 ld_frag(const unsigned* p) {
    union { unsigned u[4]; short8 v; } x;
    uint2 lo = *(const uint2*)p;
    uint2 hi = *(const uint2*)(p + 2);
    x.u[0] = lo.x; x.u[1] = lo.y; x.u[2] = hi.x; x.u[3] = hi.y;
    return x.v;
}

// ---- misc small kernels -------------------------------------------------
__global__ __launch_bounds__(256) void k_zero(float* p, int n) {
    int i = blockIdx.x * 256 + threadIdx.x;
    if (i < n) p[i] = 0.f;
}

__global__ __launch_bounds__(256) void k_stats(const float* __restrict__ obs,
                                               const float* __restrict__ act,
                                               float* __restrict__ gsum,
                                               float* __restrict__ gsq) {
    __shared__ float ssum[IN_N];
    __shared__ float ssq[IN_N];
    int a = blockIdx.x >> 5;
    int r0 = (blockIdx.x & 31) * 256;
    int t = threadIdx.x;
    if (t < IN_N) { ssum[t] = 0.f; ssq[t] = 0.f; }
    __syncthreads();
    if (t < 128) {
        const float* p = obs + ((size_t)a * B_N + r0) * O_N + t;
        float s = 0.f, q = 0.f;
#pragma unroll 4
        for (int r = 0; r < 256; ++r) {
            float v = p[(size_t)r * O_N];
            s += v; q += v * v;
        }
        ssum[t] = s; ssq[t] = q;
    } else {
        int tt = t - 128;
        int f = tt & 15, rg = tt >> 4;
        const float* p = act + ((size_t)a * B_N + r0 + rg) * ACT_N + f;
        float s = 0.f, q = 0.f;
#pragma unroll 4
        for (int i = 0; i < 32; ++i) {
            float v = p[(size_t)i * 8 * ACT_N];
            s += v; q += v * v;
        }
        atomicAdd(&ssum[O_N + f], s);
        atomicAdd(&ssq[O_N + f], q);
    }
    __syncthreads();
    if (t < IN_N) {
        atomicAdd(&gsum[a * IN_N + t], ssum[t]);
        atomicAdd(&gsq[a * IN_N + t], ssq[t]);
    }
}

__global__ __launch_bounds__(256) void k_finalize(float* gsum, float* gsq) {
    int i = blockIdx.x * 256 + threadIdx.x;
    if (i < A_N * IN_N) {
        const float invB = 1.f / (float)B_N;
        float m = gsum[i] * invB;
        float v = fmaxf(gsq[i] * invB - m * m, 0.f);
        gsum[i] = m;
        gsq[i] = rsqrtf(v + 1e-5f);
    }
}

// ---- weight prep: fp32 -> bf16, transposed to [n][k/2] packed uints -----
#define L1E 393216
#define P1E 409600
#define P2E 417792
#define CRE 679936
__global__ __launch_bounds__(256) void k_wprep(
    const float* __restrict__ W_sa, const float* __restrict__ W_s,
    const float* __restrict__ Wk, const float* __restrict__ Wsel,
    const float* __restrict__ Wv, const float* __restrict__ Wc1,
    const float* __restrict__ rstd,
    unsigned* __restrict__ wt_l1, unsigned* __restrict__ wt_p1,
    unsigned* __restrict__ wt_p2, unsigned* __restrict__ wt_cr) {
    int idx = blockIdx.x * 256 + threadIdx.x;
    if (idx < L1E) {
        int a = idx / 24576, rem = idx % 24576;
        int n = rem & 255, kp = rem >> 8;  // kp 0..95
        int k0 = 2 * kp, k1 = k0 + 1;
        float v0 = 0.f, v1 = 0.f;
        if (n < 128) {
            if (k0 < IN_N) v0 = W_sa[((size_t)a * IN_N + k0) * H_N + n] * rstd[a * IN_N + k0];
            if (k1 < IN_N) v1 = W_sa[((size_t)a * IN_N + k1) * H_N + n] * rstd[a * IN_N + k1];
        } else {
            int m = n - 128;
            if (k0 < O_N) v0 = W_s[((size_t)a * O_N + k0) * H_N + m] * rstd[a * IN_N + k0];
            if (k1 < O_N) v1 = W_s[((size_t)a * O_N + k1) * H_N + m] * rstd[a * IN_N + k1];
        }
        wt_l1[(size_t)a * 24576 + n * 96 + kp] = pack_bf2(v0, v1);
    } else if (idx < P1E) {
        int i2 = idx - L1E;
        int n = i2 & 255, kp = i2 >> 8;
        int k0 = 2 * kp;
        float v0, v1;
        if (n < 128) {
            const float* w = Wk + ((size_t)(n >> 5) * H_N) * D_N + (n & 31);
            v0 = w[(size_t)k0 * D_N]; v1 = w[(size_t)(k0 + 1) * D_N];
        } else {
            int m = n - 128;
            const float* w = Wv + ((size_t)(m >> 5) * H_N) * D_N + (m & 31);
            v0 = w[(size_t)k0 * D_N]; v1 = w[(size_t)(k0 + 1) * D_N];
        }
        wt_p1[n * 64 + kp] = pack_bf2(v0, v1);
    } else if (idx < P2E) {
        int i3 = idx - P1E;
        int n = i3 & 127, kp = i3 >> 7;
        int k0 = 2 * kp;
        const float* w = Wsel + ((size_t)(n >> 5) * H_N) * D_N + (n & 31);
        wt_p2[n * 64 + kp] = pack_bf2(w[(size_t)k0 * D_N], w[(size_t)(k0 + 1) * D_N]);
    } else if (idx < CRE) {
        int i4 = idx - P2E;
        int a = i4 >> 14, r = i4 & 16383;
        int n = r & 127, kp = r >> 7;
        int k0 = 2 * kp;
        const float* w = Wc1 + (size_t)a * 256 * H_N + n;
        wt_cr[(size_t)a * 16384 + n * 128 + kp] =
            pack_bf2(w[(size_t)k0 * H_N], w[(size_t)(k0 + 1) * H_N]);
    }
}

// ---- folded biases ------------------------------------------------------
__global__ __launch_bounds__(256) void k_bfold(
    const float* __restrict__ mean, const float* __restrict__ rstd,
    const float* __restrict__ W_sa, const float* __restrict__ W_s,
    const float* __restrict__ b_sa, const float* __restrict__ b_s,
    float* __restrict__ fb) {
    int a = blockIdx.x, c = threadIdx.x;
    float s = 0.f;
    if (c < 128) {
        for (int k = 0; k < IN_N; ++k)
            s += mean[a * IN_N + k] * rstd[a * IN_N + k] *
                 W_sa[((size_t)a * IN_N + k) * H_N + c];
        fb[a * 128 + c] = b_sa[a * H_N + c] - s;
    } else {
        int m = c - 128;
        for (int k = 0; k < O_N; ++k)
            s += mean[a * IN_N + k] * rstd[a * IN_N + k] *
                 W_s[((size_t)a * O_N + k) * H_N + m];
        fb[2048 + a * 128 + m] = b_s[a * H_N + m] - s;
    }
}

// ---- L1+proj mega-GEMM --------------------------------------------------
// z=0: sa = lrelu(X@W_sa'); sa tile -> LDS; keys = sa@Wk, vals = lrelu(sa@Wv+bv)
// z=1: se = lrelu(obs@W_s'); se -> global + LDS; sel = se@Wsel
// Block 128 rows x 128 cols, 4 waves 2x2 (wave 64x64, acc[4][4]).
__global__ __launch_bounds__(256, 3) void k_l1z(
    const float* __restrict__ obs, const float* __restrict__ act,
    const unsigned* __restrict__ wt_l1, const float* __restrict__ fb,
    const unsigned* __restrict__ wt_p1, const unsigned* __restrict__ wt_p2,
    const float* __restrict__ bv,
    unsigned short* __restrict__ se_us, unsigned short* __restrict__ keys_us,
    unsigned short* __restrict__ vals_us, unsigned short* __restrict__ sel_us,
    int b0g, int Bc) {
    __shared__ unsigned smem[(128 + 128) * 34];  // 34816 B
    unsigned* Xs = smem;
    unsigned* Ws = smem + 128 * 34;
    unsigned short* tile = (unsigned short*)smem;  // [128][136] = 34816 B
    const unsigned* tileU = (const unsigned*)smem; // [128][68]

    int a = blockIdx.y;
    int z = blockIdx.z;
    int b0 = blockIdx.x * 128;
    int t = threadIdx.x;
    int wid = t >> 6, lane = t & 63, lm = lane & 15, lq = lane >> 4;
    int wrow = (wid & 1) * 64;
    int wcol = (wid >> 1) * 64;

    int kchunks = z ? 2 : 3;
    int kstop = z ? 128 : 160;
    const float* bias = fb + z * 2048 + a * 128;

    floatx4 acc[4][4];
#pragma unroll
    for (int mt = 0; mt < 4; ++mt)
#pragma unroll
        for (int nt = 0; nt < 4; ++nt)
#pragma unroll
            for (int e = 0; e < 4; ++e) acc[mt][nt][e] = 0.f;

    const unsigned* WtA = wt_l1 + (size_t)a * 24576 + (size_t)(z * 128) * 96;

    // ---- phase A: L1 GEMM ----
    for (int c = 0; c < kchunks; ++c) {
        int kk = c * 64;
        __syncthreads();
        for (int idx = t; idx < 128 * 32; idx += 256) {
            int r = idx >> 5, kp = idx & 31;
            int k = kk + 2 * kp;
            float v0 = 0.f, v1 = 0.f;
            size_t grow = (size_t)a * B_N + b0g + b0 + r;
            if (k < O_N) {
                v0 = obs[grow * O_N + k];
                v1 = obs[grow * O_N + k + 1];
            } else if (!z && k < IN_N) {
                v0 = act[grow * ACT_N + k - O_N];
                v1 = act[grow * ACT_N + k - O_N + 1];
            }
            Xs[r * 34 + kp] = pack_bf2(v0, v1);
        }
        for (int idx = t; idx < 128 * 32; idx += 256) {
            int n = idx >> 5, kp = idx & 31;
            Ws[n * 34 + kp] = WtA[(size_t)n * 96 + (kk >> 1) + kp];
        }
        __syncthreads();
#pragma unroll
        for (int s = 0; s < 2; ++s) {
            if (kk + s * 32 >= kstop) break;
            short8 afr[4];
#pragma unroll
            for (int mt = 0; mt < 4; ++mt)
                afr[mt] = ld_frag(&Xs[(wrow + mt * 16 + lm) * 34 + s * 16 + lq * 4]);
#pragma unroll
            for (int nt = 0; nt < 4; ++nt) {
                short8 bfr = ld_frag(&Ws[(wcol + nt * 16 + lm) * 34 + s * 16 + lq * 4]);
#pragma unroll
                for (int mt = 0; mt < 4; ++mt)
                    acc[mt][nt] = __builtin_amdgcn_mfma_f32_16x16x32_bf16(
                        afr[mt], bfr, acc[mt][nt], 0, 0, 0);
            }
        }
    }

    // ---- epilogue A: lrelu -> LDS tile (and se -> global for z=1) ----
    __syncthreads();  // all waves done reading Xs/Ws
#pragma unroll
    for (int mt = 0; mt < 4; ++mt)
#pragma unroll
        for (int nt = 0; nt < 4; ++nt)
#pragma unroll
            for (int r = 0; r < 4; ++r) {
                int lrow = wrow + mt * 16 + lq * 4 + r;
                int col = wcol + nt * 16 + lm;
                float v = acc[mt][nt][r] + bias[col];
                v = v > 0.f ? v : 0.01f * v;
                unsigned short h = f2bf(v);
                tile[lrow * 136 + col] = h;
                if (z) se_us[((size_t)a * Bc + b0 + lrow) * 128 + col] = h;
            }
    __syncthreads();

    // ---- phase B: projection GEMM(s), A from LDS tile, B from L2 ----
    int passes = z ? 1 : 2;
    for (int pass = 0; pass < passes; ++pass) {
#pragma unroll
        for (int mt = 0; mt < 4; ++mt)
#pragma unroll
            for (int nt = 0; nt < 4; ++nt)
#pragma unroll
                for (int e = 0; e < 4; ++e) acc[mt][nt][e] = 0.f;
        const unsigned* wbase = z ? wt_p2 : (wt_p1 + (size_t)(pass * 128) * 64);
#pragma unroll
        for (int s = 0; s < 4; ++s) {
            short8 afr[4];
#pragma unroll
            for (int mt = 0; mt < 4; ++mt)
                afr[mt] = ld_frag(&tileU[(wrow + mt * 16 + lm) * 68 + s * 16 + lq * 4]);
#pragma unroll
            for (int nt = 0; nt < 4; ++nt) {
                int col = wcol + nt * 16 + lm;
                short8 bfr = ld_frag(wbase + (size_t)col * 64 + s * 16 + lq * 4);
#pragma unroll
                for (int mt = 0; mt < 4; ++mt)
                    acc[mt][nt] = __builtin_amdgcn_mfma_f32_16x16x32_bf16(
                        afr[mt], bfr, acc[mt][nt], 0, 0, 0);
            }
        }
        unsigned short* outp = z ? sel_us : (pass == 0 ? keys_us : vals_us);
#pragma unroll
        for (int mt = 0; mt < 4; ++mt)
#pragma unroll
            for (int nt = 0; nt < 4; ++nt)
#pragma unroll
                for (int r = 0; r < 4; ++r) {
                    int lrow = wrow + mt * 16 + lq * 4 + r;
                    int col = wcol + nt * 16 + lm;
                    float v = acc[mt][nt][r];
                    if (!z && pass == 1) {
                        v += bv[col];
                        v = v > 0.f ? v : 0.01f * v;
                    }
                    outp[((size_t)a * Bc + b0 + lrow) * 128 + col] = f2bf(v);
                }
    }
}

// ---- attention: 4 batch elems/block, wave = one batch elem --------------
// QK^T via MFMA with A/B frags straight from global; lg via wave-local LDS;
// softmax in regs; PV scalar with broadcast global reads of vals.
__global__ __launch_bounds__(256, 4) void k_attn(
    const unsigned* __restrict__ keys_u, const unsigned* __restrict__ sel_u,
    const unsigned* __restrict__ vals_u, unsigned* __restrict__ other_u,
    int Bc) {
    __shared__ float lgs[4096];  // [wave][head][i][j] = 16 KB
    int t = threadIdx.x;
    int wid = t >> 6, lane = t & 63, lm = lane & 15, lq = lane >> 4;
    int b = blockIdx.x * 4 + wid;

    floatx4 lgacc[4];
#pragma unroll
    for (int n = 0; n < 4; ++n) {
        short8 afr = ld_frag(&sel_u[((size_t)lm * Bc + b) * 64 + n * 16 + lq * 4]);
        short8 bfr = ld_frag(&keys_u[((size_t)lm * Bc + b) * 64 + n * 16 + lq * 4]);
        floatx4 z4 = {0.f, 0.f, 0.f, 0.f};
        lgacc[n] = __builtin_amdgcn_mfma_f32_16x16x32_bf16(afr, bfr, z4, 0, 0, 0);
    }
#pragma unroll
    for (int n = 0; n < 4; ++n)
#pragma unroll
        for (int r = 0; r < 4; ++r)
            lgs[((wid * 4 + n) * 16 + lq * 4 + r) * 16 + lm] =
                lgacc[n][r] * 0.17677669529663687f;
    // wave-local readback (DS in-order within wave; no barrier needed)
    int n2 = lq, i = lm;
    float lg[16];
    {
        const float4* lgp = (const float4*)&lgs[((wid * 4 + n2) * 16 + i) * 16];
#pragma unroll
        for (int c = 0; c < 4; ++c) {
            float4 v = lgp[c];
            lg[4 * c] = v.x; lg[4 * c + 1] = v.y;
            lg[4 * c + 2] = v.z; lg[4 * c + 3] = v.w;
        }
    }
    lg[i] = NEGV;
    float m = lg[0];
#pragma unroll
    for (int j = 1; j < 16; ++j) m = fmaxf(m, lg[j]);
    float sum = 0.f;
#pragma unroll
    for (int j = 0; j < 16; ++j) { lg[j] = __expf(lg[j] - m); sum += lg[j]; }
    float inv = 1.f / sum;
#pragma unroll
    for (int j = 0; j < 16; ++j) lg[j] *= inv;

    float ov[32];
#pragma unroll
    for (int u = 0; u < 32; ++u) ov[u] = 0.f;
#pragma unroll
    for (int j = 0; j < 16; ++j) {
        const uint4* vp = (const uint4*)&vals_u[((size_t)j * Bc + b) * 64 + n2 * 16];
        float w = lg[j];
#pragma unroll
        for (int c = 0; c < 4; ++c) {
            uint4 x = vp[c];
            ov[8 * c + 0] = fmaf(w, bflo(x.x), ov[8 * c + 0]);
            ov[8 * c + 1] = fmaf(w, bfhi(x.x), ov[8 * c + 1]);
            ov[8 * c + 2] = fmaf(w, bflo(x.y), ov[8 * c + 2]);
            ov[8 * c + 3] = fmaf(w, bfhi(x.y), ov[8 * c + 3]);
            ov[8 * c + 4] = fmaf(w, bflo(x.z), ov[8 * c + 4]);
            ov[8 * c + 5] = fmaf(w, bfhi(x.z), ov[8 * c + 5]);
            ov[8 * c + 6] = fmaf(w, bflo(x.w), ov[8 * c + 6]);
            ov[8 * c + 7] = fmaf(w, bfhi(x.w), ov[8 * c + 7]);
        }
    }
    uint4* orow = (uint4*)&other_u[((size_t)i * Bc + b) * 64 + n2 * 16];
#pragma unroll
    for (int c = 0; c < 4; ++c) {
        uint4 o;
        o.x = pack_bf2(ov[8 * c + 0], ov[8 * c + 1]);
        o.y = pack_bf2(ov[8 * c + 2], ov[8 * c + 3]);
        o.z = pack_bf2(ov[8 * c + 4], ov[8 * c + 5]);
        o.w = pack_bf2(ov[8 * c + 6], ov[8 * c + 7]);
        orow[c] = o;
    }
}

// ---- critic: block 64 rows x 128 cols, wave 32x64, acc[2][4] ------------
__global__ __launch_bounds__(256, 3) void k_critic(
    const unsigned* __restrict__ se_u, const unsigned* __restrict__ other_u,
    const unsigned* __restrict__ wt_cr,
    const float* __restrict__ bc1, const float* __restrict__ actions,
    const float* __restrict__ Wc2, const float* __restrict__ bc2,
    float* __restrict__ qout, int b0g, int Bc) {
    __shared__ unsigned smem[(64 + 128) * 34];
    unsigned* Xs = smem;
    unsigned* Ws = smem + 64 * 34;

    int a = blockIdx.y;
    int b0 = blockIdx.x * 64;
    int t = threadIdx.x;
    int wid = t >> 6, lane = t & 63, lm = lane & 15, lq = lane >> 4;
    int wrow = (wid & 1) * 32;
    int wcol = (wid >> 1) * 64;

    floatx4 acc[2][4];
#pragma unroll
    for (int mt = 0; mt < 2; ++mt)
#pragma unroll
        for (int nt = 0; nt < 4; ++nt)
#pragma unroll
            for (int e = 0; e < 4; ++e) acc[mt][nt][e] = 0.f;

    const unsigned* WtA = wt_cr + (size_t)a * 16384;

    for (int c = 0; c < 4; ++c) {
        int kk = c * 64;
        __syncthreads();
        const unsigned* src = (c < 2) ? se_u : other_u;
        int off = (c & 1) * 32;
        for (int idx = t; idx < 64 * 32; idx += 256) {
            int r = idx >> 5, kp = idx & 31;
            Xs[r * 34 + kp] = src[((size_t)a * Bc + b0 + r) * 64 + off + kp];
        }
        for (int idx = t; idx < 128 * 32; idx += 256) {
            int n = idx >> 5, kp = idx & 31;
            Ws[n * 34 + kp] = WtA[(size_t)n * 128 + (kk >> 1) + kp];
        }
        __syncthreads();
#pragma unroll
        for (int s = 0; s < 2; ++s) {
            short8 afr[2];
#pragma unroll
            for (int mt = 0; mt < 2; ++mt)
                afr[mt] = ld_frag(&Xs[(wrow + mt * 16 + lm) * 34 + s * 16 + lq * 4]);
#pragma unroll
            for (int nt = 0; nt < 4; ++nt) {
                short8 bfr = ld_frag(&Ws[(wcol + nt * 16 + lm) * 34 + s * 16 + lq * 4]);
#pragma unroll
                for (int mt = 0; mt < 2; ++mt)
                    acc[mt][nt] = __builtin_amdgcn_mfma_f32_16x16x32_bf16(
                        afr[mt], bfr, acc[mt][nt], 0, 0, 0);
            }
        }
    }

    __syncthreads();
    unsigned short* hbuf = (unsigned short*)smem;  // [64][132]
#pragma unroll
    for (int mt = 0; mt < 2; ++mt)
#pragma unroll
        for (int nt = 0; nt < 4; ++nt)
#pragma unroll
            for (int r = 0; r < 4; ++r) {
                int row = wrow + mt * 16 + lq * 4 + r;
                int col = wcol + nt * 16 + lm;
                float v = acc[mt][nt][r] + bc1[a * H_N + col];
                v = v > 0.f ? v : 0.01f * v;
                hbuf[row * 132 + col] = f2bf(v);
            }
    __syncthreads();
    if (t < 64) {
        size_t arow = (size_t)a * B_N + b0g + b0 + t;
        const float* ap = &actions[arow * ACT_N];
        float bestv = ap[0];
        int bi = 0;
        for (int o = 1; o < ACT_N; ++o) {
            float v = ap[o];
            if (v > bestv) { bestv = v; bi = o; }
        }
        float q = bc2[a * ACT_N + bi];
        const float* w2 = &Wc2[((size_t)a * H_N) * ACT_N + bi];
        const unsigned short* hp = &hbuf[t * 132];
#pragma unroll 8
        for (int h = 0; h < H_N; ++h)
            q = fmaf(bf2f(hp[h]), w2[(size_t)h * ACT_N], q);
        qout[arow] = q;
    }
}

extern "C" void kernel_launch(void* const* d_in, const int* in_sizes, int n_in,
                              void* d_out, int out_size, void* d_ws, size_t ws_size,
                              hipStream_t stream) {
    const float* obs     = (const float*)d_in[0];
    const float* actions = (const float*)d_in[1];
    const float* W_sa    = (const float*)d_in[2];
    const float* b_sa    = (const float*)d_in[3];
    const float* W_s     = (const float*)d_in[4];
    const float* b_s     = (const float*)d_in[5];
    const float* Wk      = (const float*)d_in[6];
    const float* Wsel    = (const float*)d_in[7];
    const float* Wv      = (const float*)d_in[8];
    const float* bv      = (const float*)d_in[9];
    const float* Wc1     = (const float*)d_in[10];
    const float* bc1     = (const float*)d_in[11];
    const float* Wc2     = (const float*)d_in[12];
    const float* bc2     = (const float*)d_in[13];
    float* out = (float*)d_out;
    char* ws = (char*)d_ws;

    size_t o = 0;
    float* gsum = (float*)(ws + o); o += 2304 * 4;
    float* gsq  = (float*)(ws + o); o += 2304 * 4;
    unsigned* wt_l1 = (unsigned*)(ws + o); o += (size_t)393216 * 4;
    unsigned* wt_p1 = (unsigned*)(ws + o); o += (size_t)16384 * 4;
    unsigned* wt_p2 = (unsigned*)(ws + o); o += (size_t)8192 * 4;
    unsigned* wt_cr = (unsigned*)(ws + o); o += (size_t)262144 * 4;
    float* fb = (float*)(ws + o); o += (size_t)4096 * 4;
    size_t fixed = o;

    // Per-slice bufs: se, keys, vals, sel, other — each 4096*Bc bytes.
    int Bc = B_N;
    while (Bc > 128 && fixed + 20480ull * Bc > ws_size) Bc >>= 1;

    unsigned short* se_us   = (unsigned short*)(ws + o); o += (size_t)A_N * Bc * 128 * 2;
    unsigned short* keys_us = (unsigned short*)(ws + o); o += (size_t)A_N * Bc * 128 * 2;
    unsigned short* vals_us = (unsigned short*)(ws + o); o += (size_t)A_N * Bc * 128 * 2;
    unsigned short* sel_us  = (unsigned short*)(ws + o); o += (size_t)A_N * Bc * 128 * 2;
    unsigned short* ot_us   = (unsigned short*)(ws + o); o += (size_t)A_N * Bc * 128 * 2;

    k_zero<<<dim3(18), 256, 0, stream>>>(gsum, 2 * A_N * IN_N);
    k_stats<<<dim3(A_N * 32), 256, 0, stream>>>(obs, actions, gsum, gsq);
    k_finalize<<<dim3(9), 256, 0, stream>>>(gsum, gsq);
    k_wprep<<<dim3(CRE / 256), 256, 0, stream>>>(W_sa, W_s, Wk, Wsel, Wv, Wc1,
                                                 gsq, wt_l1, wt_p1, wt_p2, wt_cr);
    k_bfold<<<dim3(A_N), 256, 0, stream>>>(gsum, gsq, W_sa, W_s, b_sa, b_s, fb);

    for (int b0g = 0; b0g < B_N; b0g += Bc) {
        k_l1z<<<dim3(Bc / 128, A_N, 2), 256, 0, stream>>>(
            obs, actions, wt_l1, fb, wt_p1, wt_p2, bv,
            se_us, keys_us, vals_us, sel_us, b0g, Bc);
        k_attn<<<dim3(Bc / 4), 256, 0, stream>>>(
            (const unsigned*)keys_us, (const unsigned*)sel_us,
            (const unsigned*)vals_us, (unsigned*)ot_us, Bc);
        k_critic<<<dim3(Bc / 64, A_N), 256, 0, stream>>>(
            (const unsigned*)se_us, (const unsigned*)ot_us, wt_cr, bc1,
            actions, Wc2, bc2, out, b0g, Bc);
    }
}

// Round 8
// 352.496 us; speedup vs baseline: 1.1499x; 1.1499x over previous
//
#include <hip/hip_runtime.h>
#include <hip/hip_bf16.h>

#define A_N 16
#define B_N 8192
#define O_N 128
#define ACT_N 16
#define H_N 128
#define NH_N 4
#define D_N 32
#define IN_N 144
#define NEGV -1e9f

typedef __attribute__((ext_vector_type(8))) short short8;
typedef __attribute__((ext_vector_type(4))) float floatx4;

// ---- bf16 helpers (RNE) -------------------------------------------------
static __device__ inline unsigned short f2bf(float f) {
    union { float f; unsigned u; } x{f};
    unsigned u = x.u + 0x7FFFu + ((x.u >> 16) & 1u);
    return (unsigned short)(u >> 16);
}
static __device__ inline unsigned pack_bf2(float a, float b) {
    union { float f; unsigned u; } xa{a}, xb{b};
    unsigned ua = xa.u + 0x7FFFu + ((xa.u >> 16) & 1u);
    unsigned ub = xb.u + 0x7FFFu + ((xb.u >> 16) & 1u);
    return (ua >> 16) | (ub & 0xFFFF0000u);
}
static __device__ inline float bf2f(unsigned short h) {
    union { unsigned u; float f; } x;
    x.u = ((unsigned)h) << 16;
    return x.f;
}
static __device__ inline float bflo(unsigned u) {
    union { unsigned u; float f; } x; x.u = u << 16; return x.f;
}
static __device__ inline float bfhi(unsigned u) {
    union { unsigned u; float f; } x; x.u = u & 0xFFFF0000u; return x.f;
}
static __device__ inline short8 ld_frag(const unsigned* p) {
    union { unsigned u[4]; short8 v; } x;
    uint2 lo = *(const uint2*)p;
    uint2 hi = *(const uint2*)(p + 2);
    x.u[0] = lo.x; x.u[1] = lo.y; x.u[2] = hi.x; x.u[3] = hi.y;
    return x.v;
}

// ---- misc small kernels -------------------------------------------------
__global__ __launch_bounds__(256) void k_zero(float* p, int n) {
    int i = blockIdx.x * 256 + threadIdx.x;
    if (i < n) p[i] = 0.f;
}

__global__ __launch_bounds__(256) void k_stats(const float* __restrict__ obs,
                                               const float* __restrict__ act,
                                               float* __restrict__ gsum,
                                               float* __restrict__ gsq) {
    __shared__ float ssum[IN_N];
    __shared__ float ssq[IN_N];
    int a = blockIdx.x >> 5;
    int r0 = (blockIdx.x & 31) * 256;
    int t = threadIdx.x;
    if (t < IN_N) { ssum[t] = 0.f; ssq[t] = 0.f; }
    __syncthreads();
    if (t < 128) {
        const float* p = obs + ((size_t)a * B_N + r0) * O_N + t;
        float s = 0.f, q = 0.f;
#pragma unroll 4
        for (int r = 0; r < 256; ++r) {
            float v = p[(size_t)r * O_N];
            s += v; q += v * v;
        }
        ssum[t] = s; ssq[t] = q;
    } else {
        int tt = t - 128;
        int f = tt & 15, rg = tt >> 4;
        const float* p = act + ((size_t)a * B_N + r0 + rg) * ACT_N + f;
        float s = 0.f, q = 0.f;
#pragma unroll 4
        for (int i = 0; i < 32; ++i) {
            float v = p[(size_t)i * 8 * ACT_N];
            s += v; q += v * v;
        }
        atomicAdd(&ssum[O_N + f], s);
        atomicAdd(&ssq[O_N + f], q);
    }
    __syncthreads();
    if (t < IN_N) {
        atomicAdd(&gsum[a * IN_N + t], ssum[t]);
        atomicAdd(&gsq[a * IN_N + t], ssq[t]);
    }
}

__global__ __launch_bounds__(256) void k_finalize(float* gsum, float* gsq) {
    int i = blockIdx.x * 256 + threadIdx.x;
    if (i < A_N * IN_N) {
        const float invB = 1.f / (float)B_N;
        float m = gsum[i] * invB;
        float v = fmaxf(gsq[i] * invB - m * m, 0.f);
        gsum[i] = m;
        gsq[i] = rsqrtf(v + 1e-5f);
    }
}

// ---- weight prep: fp32 -> bf16, transposed to [n][k/2] packed uints -----
#define L1E 393216
#define P1E 409600
#define P2E 417792
#define CRE 679936
__global__ __launch_bounds__(256) void k_wprep(
    const float* __restrict__ W_sa, const float* __restrict__ W_s,
    const float* __restrict__ Wk, const float* __restrict__ Wsel,
    const float* __restrict__ Wv, const float* __restrict__ Wc1,
    const float* __restrict__ rstd,
    unsigned* __restrict__ wt_l1, unsigned* __restrict__ wt_p1,
    unsigned* __restrict__ wt_p2, unsigned* __restrict__ wt_cr) {
    int idx = blockIdx.x * 256 + threadIdx.x;
    if (idx < L1E) {
        int a = idx / 24576, rem = idx % 24576;
        int n = rem & 255, kp = rem >> 8;  // kp 0..95
        int k0 = 2 * kp, k1 = k0 + 1;
        float v0 = 0.f, v1 = 0.f;
        if (n < 128) {
            if (k0 < IN_N) v0 = W_sa[((size_t)a * IN_N + k0) * H_N + n] * rstd[a * IN_N + k0];
            if (k1 < IN_N) v1 = W_sa[((size_t)a * IN_N + k1) * H_N + n] * rstd[a * IN_N + k1];
        } else {
            int m = n - 128;
            if (k0 < O_N) v0 = W_s[((size_t)a * O_N + k0) * H_N + m] * rstd[a * IN_N + k0];
            if (k1 < O_N) v1 = W_s[((size_t)a * O_N + k1) * H_N + m] * rstd[a * IN_N + k1];
        }
        wt_l1[(size_t)a * 24576 + n * 96 + kp] = pack_bf2(v0, v1);
    } else if (idx < P1E) {
        int i2 = idx - L1E;
        int n = i2 & 255, kp = i2 >> 8;
        int k0 = 2 * kp;
        float v0, v1;
        if (n < 128) {
            const float* w = Wk + ((size_t)(n >> 5) * H_N) * D_N + (n & 31);
            v0 = w[(size_t)k0 * D_N]; v1 = w[(size_t)(k0 + 1) * D_N];
        } else {
            int m = n - 128;
            const float* w = Wv + ((size_t)(m >> 5) * H_N) * D_N + (m & 31);
            v0 = w[(size_t)k0 * D_N]; v1 = w[(size_t)(k0 + 1) * D_N];
        }
        wt_p1[n * 64 + kp] = pack_bf2(v0, v1);
    } else if (idx < P2E) {
        int i3 = idx - P1E;
        int n = i3 & 127, kp = i3 >> 7;
        int k0 = 2 * kp;
        const float* w = Wsel + ((size_t)(n >> 5) * H_N) * D_N + (n & 31);
        wt_p2[n * 64 + kp] = pack_bf2(w[(size_t)k0 * D_N], w[(size_t)(k0 + 1) * D_N]);
    } else if (idx < CRE) {
        int i4 = idx - P2E;
        int a = i4 >> 14, r = i4 & 16383;
        int n = r & 127, kp = r >> 7;
        int k0 = 2 * kp;
        const float* w = Wc1 + (size_t)a * 256 * H_N + n;
        wt_cr[(size_t)a * 16384 + n * 128 + kp] =
            pack_bf2(w[(size_t)k0 * H_N], w[(size_t)(k0 + 1) * H_N]);
    }
}

// ---- folded biases ------------------------------------------------------
__global__ __launch_bounds__(256) void k_bfold(
    const float* __restrict__ mean, const float* __restrict__ rstd,
    const float* __restrict__ W_sa, const float* __restrict__ W_s,
    const float* __restrict__ b_sa, const float* __restrict__ b_s,
    float* __restrict__ fb) {
    int a = blockIdx.x, c = threadIdx.x;
    float s = 0.f;
    if (c < 128) {
        for (int k = 0; k < IN_N; ++k)
            s += mean[a * IN_N + k] * rstd[a * IN_N + k] *
                 W_sa[((size_t)a * IN_N + k) * H_N + c];
        fb[a * 128 + c] = b_sa[a * H_N + c] - s;
    } else {
        int m = c - 128;
        for (int k = 0; k < O_N; ++k)
            s += mean[a * IN_N + k] * rstd[a * IN_N + k] *
                 W_s[((size_t)a * O_N + k) * H_N + m];
        fb[2048 + a * 128 + m] = b_s[a * H_N + m] - s;
    }
}

// ---- L1+proj mega-GEMM with coalesced epilogues -------------------------
// z=0: sa tile (LDS only) -> keys, vals.  z=1: se (global+LDS) -> sel.
// All global writes staged through LDS and emitted as uint4 full rows.
__global__ __launch_bounds__(256, 3) void k_l1z(
    const float* __restrict__ obs, const float* __restrict__ act,
    const unsigned* __restrict__ wt_l1, const float* __restrict__ fb,
    const unsigned* __restrict__ wt_p1, const unsigned* __restrict__ wt_p2,
    const float* __restrict__ bv,
    unsigned* __restrict__ se_u, unsigned* __restrict__ keys_u,
    unsigned* __restrict__ vals_u, unsigned* __restrict__ sel_u,
    int b0g, int Bc) {
    __shared__ unsigned smem[(128 + 128) * 34];  // 34816 B: Xs|Ws, then tile
    __shared__ unsigned outst[64 * 68];          // 17408 B: output staging
    unsigned* Xs = smem;
    unsigned* Ws = smem + 128 * 34;
    unsigned short* tile = (unsigned short*)smem;  // [128][136]
    const unsigned* tileU = (const unsigned*)smem; // [128][68]
    unsigned short* outs = (unsigned short*)outst; // [64][136]

    int a = blockIdx.y;
    int z = blockIdx.z;
    int b0 = blockIdx.x * 128;
    int t = threadIdx.x;
    int wid = t >> 6, lane = t & 63, lm = lane & 15, lq = lane >> 4;
    int wrow = (wid & 1) * 64;
    int wcol = (wid >> 1) * 64;

    int kchunks = z ? 2 : 3;
    int kstop = z ? 128 : 160;
    const float* bias = fb + z * 2048 + a * 128;

    floatx4 acc[4][4];
#pragma unroll
    for (int mt = 0; mt < 4; ++mt)
#pragma unroll
        for (int nt = 0; nt < 4; ++nt)
#pragma unroll
            for (int e = 0; e < 4; ++e) acc[mt][nt][e] = 0.f;

    const unsigned* WtA = wt_l1 + (size_t)a * 24576 + (size_t)(z * 128) * 96;

    // ---- phase A: L1 GEMM ----
    for (int c = 0; c < kchunks; ++c) {
        int kk = c * 64;
        __syncthreads();
        for (int idx = t; idx < 128 * 32; idx += 256) {
            int r = idx >> 5, kp = idx & 31;
            int k = kk + 2 * kp;
            float v0 = 0.f, v1 = 0.f;
            size_t grow = (size_t)a * B_N + b0g + b0 + r;
            if (k < O_N) {
                v0 = obs[grow * O_N + k];
                v1 = obs[grow * O_N + k + 1];
            } else if (!z && k < IN_N) {
                v0 = act[grow * ACT_N + k - O_N];
                v1 = act[grow * ACT_N + k - O_N + 1];
            }
            Xs[r * 34 + kp] = pack_bf2(v0, v1);
        }
        for (int idx = t; idx < 128 * 32; idx += 256) {
            int n = idx >> 5, kp = idx & 31;
            Ws[n * 34 + kp] = WtA[(size_t)n * 96 + (kk >> 1) + kp];
        }
        __syncthreads();
#pragma unroll
        for (int s = 0; s < 2; ++s) {
            if (kk + s * 32 >= kstop) break;
            short8 afr[4];
#pragma unroll
            for (int mt = 0; mt < 4; ++mt)
                afr[mt] = ld_frag(&Xs[(wrow + mt * 16 + lm) * 34 + s * 16 + lq * 4]);
#pragma unroll
            for (int nt = 0; nt < 4; ++nt) {
                short8 bfr = ld_frag(&Ws[(wcol + nt * 16 + lm) * 34 + s * 16 + lq * 4]);
#pragma unroll
                for (int mt = 0; mt < 4; ++mt)
                    acc[mt][nt] = __builtin_amdgcn_mfma_f32_16x16x32_bf16(
                        afr[mt], bfr, acc[mt][nt], 0, 0, 0);
            }
        }
    }

    // ---- epilogue A: lrelu -> LDS tile ----
    __syncthreads();  // all waves done reading Xs/Ws (tile aliases them)
#pragma unroll
    for (int mt = 0; mt < 4; ++mt)
#pragma unroll
        for (int nt = 0; nt < 4; ++nt)
#pragma unroll
            for (int r = 0; r < 4; ++r) {
                int lrow = wrow + mt * 16 + lq * 4 + r;
                int col = wcol + nt * 16 + lm;
                float v = acc[mt][nt][r] + bias[col];
                v = v > 0.f ? v : 0.01f * v;
                tile[lrow * 136 + col] = f2bf(v);
            }
    __syncthreads();

    // z=1: coalesced copy tile -> se (tile stays intact for phase B reads)
    if (z) {
        for (int idx = t; idx < 128 * 16; idx += 256) {
            int row = idx >> 4, kp = idx & 15;
            uint4 v = *(const uint4*)&tileU[row * 68 + kp * 4];
            *(uint4*)&se_u[((size_t)a * Bc + b0 + row) * 64 + kp * 4] = v;
        }
    }

    // ---- phase B: projection GEMM(s), coalesced output via outstage ----
    int passes = z ? 1 : 2;
    for (int pass = 0; pass < passes; ++pass) {
#pragma unroll
        for (int mt = 0; mt < 4; ++mt)
#pragma unroll
            for (int nt = 0; nt < 4; ++nt)
#pragma unroll
                for (int e = 0; e < 4; ++e) acc[mt][nt][e] = 0.f;
        const unsigned* wbase = z ? wt_p2 : (wt_p1 + (size_t)(pass * 128) * 64);
#pragma unroll
        for (int s = 0; s < 4; ++s) {
            short8 afr[4];
#pragma unroll
            for (int mt = 0; mt < 4; ++mt)
                afr[mt] = ld_frag(&tileU[(wrow + mt * 16 + lm) * 68 + s * 16 + lq * 4]);
#pragma unroll
            for (int nt = 0; nt < 4; ++nt) {
                int col = wcol + nt * 16 + lm;
                short8 bfr = ld_frag(wbase + (size_t)col * 64 + s * 16 + lq * 4);
#pragma unroll
                for (int mt = 0; mt < 4; ++mt)
                    acc[mt][nt] = __builtin_amdgcn_mfma_f32_16x16x32_bf16(
                        afr[mt], bfr, acc[mt][nt], 0, 0, 0);
            }
        }
        unsigned* outp = z ? sel_u : (pass == 0 ? keys_u : vals_u);
        int do_bias = (!z && pass == 1);
        // two half-height rounds through outstage
#pragma unroll
        for (int h = 0; h < 2; ++h) {
            if ((wid & 1) == h) {
#pragma unroll
                for (int mt = 0; mt < 4; ++mt)
#pragma unroll
                    for (int nt = 0; nt < 4; ++nt)
#pragma unroll
                        for (int r = 0; r < 4; ++r) {
                            int lrow = mt * 16 + lq * 4 + r;  // 0..63
                            int col = wcol + nt * 16 + lm;
                            float v = acc[mt][nt][r];
                            if (do_bias) {
                                v += bv[col];
                                v = v > 0.f ? v : 0.01f * v;
                            }
                            outs[lrow * 136 + col] = f2bf(v);
                        }
            }
            __syncthreads();
            for (int idx = t; idx < 64 * 16; idx += 256) {
                int row = idx >> 4, kp = idx & 15;
                uint4 v = *(const uint4*)&outst[row * 68 + kp * 4];
                *(uint4*)&outp[((size_t)a * Bc + b0 + h * 64 + row) * 64 + kp * 4] = v;
            }
            __syncthreads();
        }
    }
}

// ---- attention: 4 batch elems/block, wave = one batch elem --------------
__global__ __launch_bounds__(256, 4) void k_attn(
    const unsigned* __restrict__ keys_u, const unsigned* __restrict__ sel_u,
    const unsigned* __restrict__ vals_u, unsigned* __restrict__ other_u,
    int Bc) {
    __shared__ float lgs[4096];  // [wave][head][i][j] = 16 KB
    int t = threadIdx.x;
    int wid = t >> 6, lane = t & 63, lm = lane & 15, lq = lane >> 4;
    int b = blockIdx.x * 4 + wid;

    floatx4 lgacc[4];
#pragma unroll
    for (int n = 0; n < 4; ++n) {
        short8 afr = ld_frag(&sel_u[((size_t)lm * Bc + b) * 64 + n * 16 + lq * 4]);
        short8 bfr = ld_frag(&keys_u[((size_t)lm * Bc + b) * 64 + n * 16 + lq * 4]);
        floatx4 z4 = {0.f, 0.f, 0.f, 0.f};
        lgacc[n] = __builtin_amdgcn_mfma_f32_16x16x32_bf16(afr, bfr, z4, 0, 0, 0);
    }
#pragma unroll
    for (int n = 0; n < 4; ++n)
#pragma unroll
        for (int r = 0; r < 4; ++r)
            lgs[((wid * 4 + n) * 16 + lq * 4 + r) * 16 + lm] =
                lgacc[n][r] * 0.17677669529663687f;
    int n2 = lq, i = lm;
    float lg[16];
    {
        const float4* lgp = (const float4*)&lgs[((wid * 4 + n2) * 16 + i) * 16];
#pragma unroll
        for (int c = 0; c < 4; ++c) {
            float4 v = lgp[c];
            lg[4 * c] = v.x; lg[4 * c + 1] = v.y;
            lg[4 * c + 2] = v.z; lg[4 * c + 3] = v.w;
        }
    }
    lg[i] = NEGV;
    float m = lg[0];
#pragma unroll
    for (int j = 1; j < 16; ++j) m = fmaxf(m, lg[j]);
    float sum = 0.f;
#pragma unroll
    for (int j = 0; j < 16; ++j) { lg[j] = __expf(lg[j] - m); sum += lg[j]; }
    float inv = 1.f / sum;
#pragma unroll
    for (int j = 0; j < 16; ++j) lg[j] *= inv;

    float ov[32];
#pragma unroll
    for (int u = 0; u < 32; ++u) ov[u] = 0.f;
#pragma unroll
    for (int j = 0; j < 16; ++j) {
        const uint4* vp = (const uint4*)&vals_u[((size_t)j * Bc + b) * 64 + n2 * 16];
        float w = lg[j];
#pragma unroll
        for (int c = 0; c < 4; ++c) {
            uint4 x = vp[c];
            ov[8 * c + 0] = fmaf(w, bflo(x.x), ov[8 * c + 0]);
            ov[8 * c + 1] = fmaf(w, bfhi(x.x), ov[8 * c + 1]);
            ov[8 * c + 2] = fmaf(w, bflo(x.y), ov[8 * c + 2]);
            ov[8 * c + 3] = fmaf(w, bfhi(x.y), ov[8 * c + 3]);
            ov[8 * c + 4] = fmaf(w, bflo(x.z), ov[8 * c + 4]);
            ov[8 * c + 5] = fmaf(w, bfhi(x.z), ov[8 * c + 5]);
            ov[8 * c + 6] = fmaf(w, bflo(x.w), ov[8 * c + 6]);
            ov[8 * c + 7] = fmaf(w, bfhi(x.w), ov[8 * c + 7]);
        }
    }
    uint4* orow = (uint4*)&other_u[((size_t)i * Bc + b) * 64 + n2 * 16];
#pragma unroll
    for (int c = 0; c < 4; ++c) {
        uint4 o;
        o.x = pack_bf2(ov[8 * c + 0], ov[8 * c + 1]);
        o.y = pack_bf2(ov[8 * c + 2], ov[8 * c + 3]);
        o.z = pack_bf2(ov[8 * c + 4], ov[8 * c + 5]);
        o.w = pack_bf2(ov[8 * c + 6], ov[8 * c + 7]);
        orow[c] = o;
    }
}

// ---- critic: block 64 rows x 128 cols, wave 32x64, acc[2][4] ------------
__global__ __launch_bounds__(256, 3) void k_critic(
    const unsigned* __restrict__ se_u, const unsigned* __restrict__ other_u,
    const unsigned* __restrict__ wt_cr,
    const float* __restrict__ bc1, const float* __restrict__ actions,
    const float* __restrict__ Wc2, const float* __restrict__ bc2,
    float* __restrict__ qout, int b0g, int Bc) {
    __shared__ unsigned smem[(64 + 128) * 34];
    unsigned* Xs = smem;
    unsigned* Ws = smem + 64 * 34;

    int a = blockIdx.y;
    int b0 = blockIdx.x * 64;
    int t = threadIdx.x;
    int wid = t >> 6, lane = t & 63, lm = lane & 15, lq = lane >> 4;
    int wrow = (wid & 1) * 32;
    int wcol = (wid >> 1) * 64;

    floatx4 acc[2][4];
#pragma unroll
    for (int mt = 0; mt < 2; ++mt)
#pragma unroll
        for (int nt = 0; nt < 4; ++nt)
#pragma unroll
            for (int e = 0; e < 4; ++e) acc[mt][nt][e] = 0.f;

    const unsigned* WtA = wt_cr + (size_t)a * 16384;

    for (int c = 0; c < 4; ++c) {
        int kk = c * 64;
        __syncthreads();
        const unsigned* src = (c < 2) ? se_u : other_u;
        int off = (c & 1) * 32;
        for (int idx = t; idx < 64 * 32; idx += 256) {
            int r = idx >> 5, kp = idx & 31;
            Xs[r * 34 + kp] = src[((size_t)a * Bc + b0 + r) * 64 + off + kp];
        }
        for (int idx = t; idx < 128 * 32; idx += 256) {
            int n = idx >> 5, kp = idx & 31;
            Ws[n * 34 + kp] = WtA[(size_t)n * 128 + (kk >> 1) + kp];
        }
        __syncthreads();
#pragma unroll
        for (int s = 0; s < 2; ++s) {
            short8 afr[2];
#pragma unroll
            for (int mt = 0; mt < 2; ++mt)
                afr[mt] = ld_frag(&Xs[(wrow + mt * 16 + lm) * 34 + s * 16 + lq * 4]);
#pragma unroll
            for (int nt = 0; nt < 4; ++nt) {
                short8 bfr = ld_frag(&Ws[(wcol + nt * 16 + lm) * 34 + s * 16 + lq * 4]);
#pragma unroll
                for (int mt = 0; mt < 2; ++mt)
                    acc[mt][nt] = __builtin_amdgcn_mfma_f32_16x16x32_bf16(
                        afr[mt], bfr, acc[mt][nt], 0, 0, 0);
            }
        }
    }

    __syncthreads();
    unsigned short* hbuf = (unsigned short*)smem;  // [64][132]
#pragma unroll
    for (int mt = 0; mt < 2; ++mt)
#pragma unroll
        for (int nt = 0; nt < 4; ++nt)
#pragma unroll
            for (int r = 0; r < 4; ++r) {
                int row = wrow + mt * 16 + lq * 4 + r;
                int col = wcol + nt * 16 + lm;
                float v = acc[mt][nt][r] + bc1[a * H_N + col];
                v = v > 0.f ? v : 0.01f * v;
                hbuf[row * 132 + col] = f2bf(v);
            }
    __syncthreads();
    if (t < 64) {
        size_t arow = (size_t)a * B_N + b0g + b0 + t;
        const float* ap = &actions[arow * ACT_N];
        float bestv = ap[0];
        int bi = 0;
        for (int o = 1; o < ACT_N; ++o) {
            float v = ap[o];
            if (v > bestv) { bestv = v; bi = o; }
        }
        float q = bc2[a * ACT_N + bi];
        const float* w2 = &Wc2[((size_t)a * H_N) * ACT_N + bi];
        const unsigned short* hp = &hbuf[t * 132];
#pragma unroll 8
        for (int h = 0; h < H_N; ++h)
            q = fmaf(bf2f(hp[h]), w2[(size_t)h * ACT_N], q);
        qout[arow] = q;
    }
}

extern "C" void kernel_launch(void* const* d_in, const int* in_sizes, int n_in,
                              void* d_out, int out_size, void* d_ws, size_t ws_size,
                              hipStream_t stream) {
    const float* obs     = (const float*)d_in[0];
    const float* actions = (const float*)d_in[1];
    const float* W_sa    = (const float*)d_in[2];
    const float* b_sa    = (const float*)d_in[3];
    const float* W_s     = (const float*)d_in[4];
    const float* b_s     = (const float*)d_in[5];
    const float* Wk      = (const float*)d_in[6];
    const float* Wsel    = (const float*)d_in[7];
    const float* Wv      = (const float*)d_in[8];
    const float* bv      = (const float*)d_in[9];
    const float* Wc1     = (const float*)d_in[10];
    const float* bc1     = (const float*)d_in[11];
    const float* Wc2     = (const float*)d_in[12];
    const float* bc2     = (const float*)d_in[13];
    float* out = (float*)d_out;
    char* ws = (char*)d_ws;

    size_t o = 0;
    float* gsum = (float*)(ws + o); o += 2304 * 4;
    float* gsq  = (float*)(ws + o); o += 2304 * 4;
    unsigned* wt_l1 = (unsigned*)(ws + o); o += (size_t)393216 * 4;
    unsigned* wt_p1 = (unsigned*)(ws + o); o += (size_t)16384 * 4;
    unsigned* wt_p2 = (unsigned*)(ws + o); o += (size_t)8192 * 4;
    unsigned* wt_cr = (unsigned*)(ws + o); o += (size_t)262144 * 4;
    float* fb = (float*)(ws + o); o += (size_t)4096 * 4;
    size_t fixed = o;

    // Per-slice bufs: se, keys, vals, sel, other — each 4096*Bc bytes.
    int Bc = B_N;
    while (Bc > 128 && fixed + 20480ull * Bc > ws_size) Bc >>= 1;

    unsigned* se_u   = (unsigned*)(ws + o); o += (size_t)A_N * Bc * 128 * 2;
    unsigned* keys_u = (unsigned*)(ws + o); o += (size_t)A_N * Bc * 128 * 2;
    unsigned* vals_u = (unsigned*)(ws + o); o += (size_t)A_N * Bc * 128 * 2;
    unsigned* sel_u  = (unsigned*)(ws + o); o += (size_t)A_N * Bc * 128 * 2;
    unsigned* ot_u   = (unsigned*)(ws + o); o += (size_t)A_N * Bc * 128 * 2;

    k_zero<<<dim3(18), 256, 0, stream>>>(gsum, 2 * A_N * IN_N);
    k_stats<<<dim3(A_N * 32), 256, 0, stream>>>(obs, actions, gsum, gsq);
    k_finalize<<<dim3(9), 256, 0, stream>>>(gsum, gsq);
    k_wprep<<<dim3(CRE / 256), 256, 0, stream>>>(W_sa, W_s, Wk, Wsel, Wv, Wc1,
                                                 gsq, wt_l1, wt_p1, wt_p2, wt_cr);
    k_bfold<<<dim3(A_N), 256, 0, stream>>>(gsum, gsq, W_sa, W_s, b_sa, b_s, fb);

    for (int b0g = 0; b0g < B_N; b0g += Bc) {
        k_l1z<<<dim3(Bc / 128, A_N, 2), 256, 0, stream>>>(
            obs, actions, wt_l1, fb, wt_p1, wt_p2, bv,
            se_u, keys_u, vals_u, sel_u, b0g, Bc);
        k_attn<<<dim3(Bc / 4), 256, 0, stream>>>(
            keys_u, sel_u, vals_u, ot_u, Bc);
        k_critic<<<dim3(Bc / 64, A_N), 256, 0, stream>>>(
            se_u, ot_u, wt_cr, bc1, actions, Wc2, bc2, out, b0g, Bc);
    }
}